// Round 3
// baseline (78.683 us; speedup 1.0000x reference)
//
#include <hip/hip_runtime.h>
#include <hip/hip_bf16.h>

typedef __attribute__((ext_vector_type(8))) short s16x8;
typedef __attribute__((ext_vector_type(4))) float f32x4;

#define B_  8
#define N_  2048
#define F_  128
#define BM  32
#define BK  64
#define NT  (N_/BK)     // 32 k-tiles
#define NRB (N_/BM)     // 64 row-blocks per batch

// ws layout: [0,64K) dinv | [64K, 64K+4M) xt | [8M, 8M+67M) adjb
#define WS_XT   (65536)
#define WS_ADJB ((size_t)8 << 20)
#define ADJB_BYTES ((size_t)B_ * NRB * NT * 4096)

__device__ __forceinline__ short bfc(float f) {
  __hip_bfloat16 h = __float2bfloat16(f);   // RNE
  return __builtin_bit_cast(short, h);
}

__device__ __forceinline__ void gload16(const void* g, void* l) {
  __builtin_amdgcn_global_load_lds(
      (const __attribute__((address_space(1))) unsigned*)g,
      (__attribute__((address_space(3))) unsigned*)l, 16, 0, 0);
}
__device__ __forceinline__ void gload4(const void* g, void* l) {
  __builtin_amdgcn_global_load_lds(
      (const __attribute__((address_space(1))) unsigned*)g,
      (__attribute__((address_space(3))) unsigned*)l, 4, 0, 0);
}

// ============ pass 1: rowsum->dinv AND adjb = bf16(adj + I), tiled+swizzled ============
// adjb tile (b, rb, t): [32 rows][64 cols] bf16, elem (r,c) at r*64 + (c ^ ((r&7)<<3))
__global__ __launch_bounds__(256) void k_pass1(const float* __restrict__ adj,
                                               float* __restrict__ dinv,
                                               unsigned short* __restrict__ adjb) {
  const int b  = blockIdx.x >> 7;            // 128 blocks per batch
  const int r0 = (blockIdx.x & 127) * 16;    // 16 rows per block
  const int rl = threadIdx.x >> 4;
  const int j  = threadIdx.x & 15;
  const int r  = r0 + rl;                    // row within batch
  const int c0 = j * 4;
  const float* row = adj + ((size_t)b * N_ + r) * N_;
  const int rb  = r >> 5;
  const int rit = r & 31;
  unsigned short* tb0 = adjb + ((size_t)(b * NRB + rb) * NT) * 2048 + rit * 64;
  const int swz = (r & 7) << 3;
  const int cs  = c0 ^ swz;

  float s = 0.f;
#pragma unroll 4
  for (int t = 0; t < NT; ++t) {
    const int cg = t * BK + c0;
    float4 v = *reinterpret_cast<const float4*>(row + cg);
    if (r >= cg && r < cg + 4) (&v.x)[r - cg] += 1.0f;   // fold self-loop
    s += (v.x + v.y) + (v.z + v.w);
    short4 h;
    h.x = bfc(v.x); h.y = bfc(v.y); h.z = bfc(v.z); h.w = bfc(v.w);
    *reinterpret_cast<short4*>(tb0 + (size_t)t * 2048 + cs) = h;
  }
  s += __shfl_xor(s, 1); s += __shfl_xor(s, 2);
  s += __shfl_xor(s, 4); s += __shfl_xor(s, 8);
  if (j == 0) dinv[b * N_ + r] = 1.0f / sqrtf(s);
}

// ============ pass 1b: xt[b][t][f][k_swz] = bf16(d_m * x) (unchanged) ============
__global__ __launch_bounds__(256) void k_prep(const float* __restrict__ x,
                                              const float* __restrict__ dinv,
                                              unsigned short* __restrict__ xt) {
  __shared__ short s[F_ * 64];
  const int b  = blockIdx.x >> 5;
  const int t  = blockIdx.x & 31;
  const int rp = threadIdx.x >> 3;
  const int f0 = (threadIdx.x & 7) * 16;
  const int r0 = rp * 2;
  const float* x0 = x + ((size_t)(b * N_) + t * 64 + r0) * F_ + f0;
  const float d0 = dinv[b * N_ + t * 64 + r0];
  const float d1 = dinv[b * N_ + t * 64 + r0 + 1];
#pragma unroll
  for (int u = 0; u < 16; u += 4) {
    float4 v0 = *reinterpret_cast<const float4*>(x0 + u);
    float4 v1 = *reinterpret_cast<const float4*>(x0 + F_ + u);
    float a0[4] = {v0.x, v0.y, v0.z, v0.w};
    float a1[4] = {v1.x, v1.y, v1.z, v1.w};
#pragma unroll
    for (int k = 0; k < 4; ++k) {
      const int f = f0 + u + k;
      unsigned lo = (unsigned short)bfc(a0[k] * d0);
      unsigned hi = (unsigned short)bfc(a1[k] * d1);
      *reinterpret_cast<unsigned*>(&s[f * 64 + (r0 ^ ((f & 7) << 3))]) = lo | (hi << 16);
    }
  }
  __syncthreads();
  const s16x8* sp = reinterpret_cast<const s16x8*>(s);
  s16x8* op = reinterpret_cast<s16x8*>(xt + (size_t)blockIdx.x * 8192);
#pragma unroll
  for (int k = 0; k < 4; ++k) op[threadIdx.x * 4 + k] = sp[threadIdx.x * 4 + k];
}

// ============ pass 2: pure-DMA aggregate + linear ============
__global__ __launch_bounds__(512, 4) void k_gcn3(const unsigned short* __restrict__ adjb,
                                                 const unsigned short* __restrict__ xt,
                                                 const float* __restrict__ W,
                                                 const float* __restrict__ bias,
                                                 const float* __restrict__ dinv,
                                                 float* __restrict__ out) {
  __shared__ short s_adj[3 * 2048];   // 3 x 4 KB
  __shared__ short s_xt[3 * 8192];    // 3 x 16 KB
  short* const s_o1 = s_xt;           // epilogue alias [32][136]

  const int tid  = threadIdx.x;
  const int lane = tid & 63;
  const int wv   = tid >> 6;
  const int wrow = wv & 1;
  const int wcol = wv >> 1;

  const int batch = blockIdx.x & 7;   // batch pinned per XCD
  const int rb    = blockIdx.x >> 3;
  const int n0    = rb * BM;

  // ---- W fragments into registers (32 VGPR) ----
  s16x8 wfr[2][4];
#pragma unroll
  for (int ot = 0; ot < 2; ++ot) {
#pragma unroll
    for (int kk = 0; kk < 4; ++kk) {
      const int o  = wcol * 32 + ot * 16 + (lane & 15);
      const int f0 = kk * 32 + (lane >> 4) * 8;
      float4 v0 = *reinterpret_cast<const float4*>(W + o * F_ + f0);
      float4 v1 = *reinterpret_cast<const float4*>(W + o * F_ + f0 + 4);
      s16x8 h;
      h[0] = bfc(v0.x); h[1] = bfc(v0.y); h[2] = bfc(v0.z); h[3] = bfc(v0.w);
      h[4] = bfc(v1.x); h[5] = bfc(v1.y); h[6] = bfc(v1.z); h[7] = bfc(v1.w);
      wfr[ot][kk] = h;
    }
  }
  asm volatile("s_waitcnt vmcnt(0)" ::: "memory");
  __builtin_amdgcn_sched_barrier(0);

  const unsigned short* atile = adjb + ((size_t)(batch * NRB + rb) * NT) * 2048;
  const unsigned short* xtb   = xt + (size_t)batch * NT * 8192;

  // per-step issues (uniform 4 VMEM ops per thread: 2x gload16 X, 2x gload4 adj)
  auto issueX = [&](int t, int buf) {
    const unsigned short* src = xtb + (size_t)t * 8192;
    short* dst = s_xt + buf * 8192;
    gload16(src + tid * 8, dst + tid * 8);
    gload16(src + 4096 + tid * 8, dst + 4096 + tid * 8);
  };
  auto issueA = [&](int t, int buf) {
    const unsigned short* src = atile + (size_t)t * 2048;
    short* dst = s_adj + buf * 2048;
    gload4(src + tid * 2, dst + tid * 2);
    gload4(src + 1024 + tid * 2, dst + 1024 + tid * 2);
  };

  f32x4 acc[2] = {};

  // prologue: depth-2 fill
  issueX(0, 0); issueA(0, 0);
  issueX(1, 1); issueA(1, 1);

  int bc = 0;
#pragma unroll 1
  for (int t = 0; t < NT; ++t) {
    if (t < NT - 1) asm volatile("s_waitcnt vmcnt(4)" ::: "memory");
    else            asm volatile("s_waitcnt vmcnt(0)" ::: "memory");
    __builtin_amdgcn_s_barrier();
    __builtin_amdgcn_sched_barrier(0);
    if (t + 2 < NT) {
      int bn = bc + 2; if (bn >= 3) bn -= 3;
      issueX(t + 2, bn);
      issueA(t + 2, bn);
    }
    // compute tile t from buffer bc
    {
      const short* sa = &s_adj[bc * 2048];
      const short* sx = &s_xt[bc * 8192];
      const int row  = wrow * 16 + (lane & 15);
      const int swzr = (row & 7) << 3;
      const int krun = (lane >> 4) * 8;
      s16x8 a0 = *reinterpret_cast<const s16x8*>(sa + row * 64 + (krun ^ swzr));
      s16x8 a1 = *reinterpret_cast<const s16x8*>(sa + row * 64 + ((32 + krun) ^ swzr));
#pragma unroll
      for (int ct = 0; ct < 2; ++ct) {
        const int f    = wcol * 32 + ct * 16 + (lane & 15);
        const int swzf = (f & 7) << 3;
        s16x8 b0 = *reinterpret_cast<const s16x8*>(sx + f * 64 + (krun ^ swzf));
        s16x8 b1 = *reinterpret_cast<const s16x8*>(sx + f * 64 + ((32 + krun) ^ swzf));
        acc[ct] = __builtin_amdgcn_mfma_f32_16x16x32_bf16(a0, b0, acc[ct], 0, 0, 0);
        acc[ct] = __builtin_amdgcn_mfma_f32_16x16x32_bf16(a1, b1, acc[ct], 0, 0, 0);
      }
    }
    bc = (bc + 1 == 3) ? 0 : bc + 1;
  }

  // ---- epilogue: out1 = d_n * acc (self-loop already in adjb) ----
  __syncthreads();
  {
    const int lr4 = (lane >> 4) * 4;
    const int lc  = lane & 15;
#pragma unroll
    for (int r = 0; r < 4; ++r) {
      const int nl = wrow * 16 + lr4 + r;
      const float dn = dinv[batch * N_ + n0 + nl];
#pragma unroll
      for (int ct = 0; ct < 2; ++ct) {
        const int f = wcol * 32 + ct * 16 + lc;
        s_o1[nl * 136 + f] = bfc(dn * acc[ct][r]);
      }
    }
  }
  __syncthreads();

  f32x4 acc2[2] = {};
  {
    const int lc   = lane & 15;
    const int krun = (lane >> 4) * 8;
#pragma unroll
    for (int kk = 0; kk < 4; ++kk) {
      s16x8 af = *reinterpret_cast<const s16x8*>(&s_o1[(wrow * 16 + lc) * 136 + kk * 32 + krun]);
#pragma unroll
      for (int ot = 0; ot < 2; ++ot)
        acc2[ot] = __builtin_amdgcn_mfma_f32_16x16x32_bf16(af, wfr[ot][kk], acc2[ot], 0, 0, 0);
    }
  }
  {
    const int lr4 = (lane >> 4) * 4;
    const int lc  = lane & 15;
#pragma unroll
    for (int ot = 0; ot < 2; ++ot) {
      const int o  = wcol * 32 + ot * 16 + lc;
      const float bb = bias[o];
#pragma unroll
      for (int r = 0; r < 4; ++r) {
        const int nl = wrow * 16 + lr4 + r;
        out[(size_t)(batch * N_ + n0 + nl) * F_ + o] = acc2[ot][r] + bb;
      }
    }
  }
}

// ============ fallback (round-1 style, needs only 64 KB ws) ============
__global__ __launch_bounds__(256) void k_deg(const float* __restrict__ adj,
                                             float* __restrict__ dinv) {
  const int row  = blockIdx.x * 4 + (threadIdx.x >> 6);
  const int lane = threadIdx.x & 63;
  const float* p = adj + (size_t)row * N_;
  float s = 0.f;
#pragma unroll
  for (int it = 0; it < 8; ++it) {
    float4 v = *reinterpret_cast<const float4*>(p + it * 256 + lane * 4);
    s += (v.x + v.y) + (v.z + v.w);
  }
#pragma unroll
  for (int off = 32; off > 0; off >>= 1) s += __shfl_down(s, off);
  if (lane == 0) dinv[row] = 1.0f / sqrtf(s + 1.0f);
}

__global__ __launch_bounds__(512) void k_gcn_fb(const float* __restrict__ adj,
                                                const float* __restrict__ x,
                                                const float* __restrict__ W,
                                                const float* __restrict__ bias,
                                                const float* __restrict__ dinv,
                                                float* __restrict__ out) {
  __shared__ short s_mem[64 * 72 + F_ * 72];
  __shared__ short s_w[F_ * 136];
  short* const s_adj = s_mem;
  short* const s_xb  = s_mem + 64 * 72;
  short* const s_o1  = s_mem;

  const int tid  = threadIdx.x;
  const int lane = tid & 63;
  const int wv   = tid >> 6;
  const int wrow = wv & 3;
  const int whal = wv >> 2;

  const int batch = blockIdx.x & 7;
  const int n0    = (blockIdx.x >> 3) * 64;

  {
    const int o  = tid >> 2;
    const int f0 = (tid & 3) * 32;
    const float* wp = W + o * F_ + f0;
#pragma unroll
    for (int u = 0; u < 8; ++u) {
      float4 v = *reinterpret_cast<const float4*>(wp + u * 4);
      short4 h;
      h.x = bfc(v.x); h.y = bfc(v.y); h.z = bfc(v.z); h.w = bfc(v.w);
      *reinterpret_cast<short4*>(&s_w[o * 136 + f0 + u * 4]) = h;
    }
  }

  const int ai  = tid >> 3;
  const int aj  = (tid & 7) * 8;
  const int xk2 = tid >> 4;
  const int xf0 = (tid & 15) * 8;

  const float* adj_row = adj + (size_t)(batch * N_ + n0 + ai) * N_;
  const float* x_b     = x + (size_t)batch * N_ * F_;
  const float* dv_b    = dinv + batch * N_;

  float4 ra0, ra1, rx0, rx1, rx2, rx3;
  float rd0, rd1;

  auto issue = [&](int k0) {
    ra0 = *reinterpret_cast<const float4*>(adj_row + k0 + aj);
    ra1 = *reinterpret_cast<const float4*>(adj_row + k0 + aj + 4);
    const float* xr = x_b + (size_t)(k0 + 2 * xk2) * F_ + xf0;
    rx0 = *reinterpret_cast<const float4*>(xr);
    rx1 = *reinterpret_cast<const float4*>(xr + 4);
    rx2 = *reinterpret_cast<const float4*>(xr + F_);
    rx3 = *reinterpret_cast<const float4*>(xr + F_ + 4);
    rd0 = dv_b[k0 + 2 * xk2];
    rd1 = dv_b[k0 + 2 * xk2 + 1];
  };

  f32x4 acc[4] = {};
  issue(0);
#pragma unroll 1
  for (int t = 0; t < N_ / 64; ++t) {
    __syncthreads();
    {
      s16x8 h;
      h[0] = bfc(ra0.x); h[1] = bfc(ra0.y); h[2] = bfc(ra0.z); h[3] = bfc(ra0.w);
      h[4] = bfc(ra1.x); h[5] = bfc(ra1.y); h[6] = bfc(ra1.z); h[7] = bfc(ra1.w);
      *reinterpret_cast<s16x8*>(&s_adj[ai * 72 + aj]) = h;
    }
    {
      float a0[8] = {rx0.x, rx0.y, rx0.z, rx0.w, rx1.x, rx1.y, rx1.z, rx1.w};
      float a1[8] = {rx2.x, rx2.y, rx2.z, rx2.w, rx3.x, rx3.y, rx3.z, rx3.w};
      const int kbase = (2 * xk2) ^ ((tid & 7) << 3);
#pragma unroll
      for (int u = 0; u < 8; ++u) {
        unsigned lo = (unsigned short)bfc(a0[u] * rd0);
        unsigned hi = (unsigned short)bfc(a1[u] * rd1);
        *reinterpret_cast<unsigned*>(&s_xb[(xf0 + u) * 72 + kbase]) = lo | (hi << 16);
      }
    }
    if (t + 1 < N_ / 64) issue((t + 1) * 64);
    __syncthreads();
    {
      const int arow = (wrow * 16 + (lane & 15)) * 72 + ((lane >> 4) * 8);
      s16x8 a0 = *reinterpret_cast<const s16x8*>(&s_adj[arow]);
      s16x8 a1 = *reinterpret_cast<const s16x8*>(&s_adj[arow + 32]);
      const int krun = (lane >> 4) * 8;
#pragma unroll
      for (int ct = 0; ct < 4; ++ct) {
        const int f   = whal * 64 + ct * 16 + (lane & 15);
        const int xsw = ((f >> 3) & 7) << 3;
        s16x8 b0 = *reinterpret_cast<const s16x8*>(&s_xb[f * 72 + (krun ^ xsw)]);
        s16x8 b1 = *reinterpret_cast<const s16x8*>(&s_xb[f * 72 + ((krun + 32) ^ xsw)]);
        acc[ct] = __builtin_amdgcn_mfma_f32_16x16x32_bf16(a0, b0, acc[ct], 0, 0, 0);
        acc[ct] = __builtin_amdgcn_mfma_f32_16x16x32_bf16(a1, b1, acc[ct], 0, 0, 0);
      }
    }
  }

  __syncthreads();
  {
    const int lr4 = (lane >> 4) * 4;
    const int lc  = lane & 15;
#pragma unroll
    for (int r = 0; r < 4; ++r) {
      const int nl = wrow * 16 + lr4 + r;
      const float dn = dv_b[n0 + nl];
      const float* xrow = x_b + (size_t)(n0 + nl) * F_;
#pragma unroll
      for (int ct = 0; ct < 4; ++ct) {
        const int f = whal * 64 + ct * 16 + lc;
        s_o1[nl * 136 + f] = bfc(dn * acc[ct][r] + dn * dn * xrow[f]);
      }
    }
  }
  __syncthreads();

  f32x4 acc2[4] = {};
  {
    const int lc   = lane & 15;
    const int krun = (lane >> 4) * 8;
#pragma unroll
    for (int kk = 0; kk < 4; ++kk) {
      s16x8 af = *reinterpret_cast<const s16x8*>(&s_o1[(wrow * 16 + lc) * 136 + kk * 32 + krun]);
#pragma unroll
      for (int ot = 0; ot < 4; ++ot) {
        const int o = whal * 64 + ot * 16 + lc;
        s16x8 bf8 = *reinterpret_cast<const s16x8*>(&s_w[o * 136 + kk * 32 + krun]);
        acc2[ot] = __builtin_amdgcn_mfma_f32_16x16x32_bf16(af, bf8, acc2[ot], 0, 0, 0);
      }
    }
  }
  {
    const int lr4 = (lane >> 4) * 4;
    const int lc  = lane & 15;
#pragma unroll
    for (int ot = 0; ot < 4; ++ot) {
      const int o  = whal * 64 + ot * 16 + lc;
      const float bb = bias[o];
#pragma unroll
      for (int r = 0; r < 4; ++r) {
        const int nl = wrow * 16 + lr4 + r;
        out[(size_t)(batch * N_ + n0 + nl) * F_ + o] = acc2[ot][r] + bb;
      }
    }
  }
}

extern "C" void kernel_launch(void* const* d_in, const int* in_sizes, int n_in,
                              void* d_out, int out_size, void* d_ws, size_t ws_size,
                              hipStream_t stream) {
  const float* x   = (const float*)d_in[0];
  const float* adj = (const float*)d_in[1];
  const float* W   = (const float*)d_in[2];
  const float* b   = (const float*)d_in[3];
  float* outp = (float*)d_out;
  float* dinv = (float*)d_ws;
  unsigned short* xt   = (unsigned short*)((char*)d_ws + WS_XT);
  unsigned short* adjb = (unsigned short*)((char*)d_ws + WS_ADJB);

  if (ws_size >= WS_ADJB + ADJB_BYTES) {
    k_pass1<<<B_ * (N_ / 16), 256, 0, stream>>>(adj, dinv, adjb);
    k_prep<<<B_ * NT, 256, 0, stream>>>(x, dinv, xt);
    k_gcn3<<<B_ * NRB, 512, 0, stream>>>(adjb, xt, W, b, dinv, outp);
  } else {
    k_deg<<<(B_ * N_) / 4, 256, 0, stream>>>(adj, dinv);
    k_gcn_fb<<<B_ * (N_ / 64), 512, 0, stream>>>(adj, x, W, b, dinv, outp);
  }
}

// Round 4
// 63.203 us; speedup vs baseline: 1.2449x; 1.2449x over previous
//
#include <hip/hip_runtime.h>
#include <hip/hip_bf16.h>

typedef __attribute__((ext_vector_type(8))) short s16x8;
typedef __attribute__((ext_vector_type(4))) float f32x4;

#define B_  8
#define N_  2048
#define F_  128
#define BM  32
#define BK  64
#define NT  (N_/BK)     // 32 k-tiles
#define NRB (N_/BM)     // 64 row-blocks per batch
#define WS_XT (65536)

__device__ __forceinline__ short bfc(float f) {
  __hip_bfloat16 h = __float2bfloat16(f);   // RNE
  return __builtin_bit_cast(short, h);
}

__device__ __forceinline__ void gload16(const void* g, void* l) {
  __builtin_amdgcn_global_load_lds(
      (const __attribute__((address_space(1))) unsigned*)g,
      (__attribute__((address_space(3))) unsigned*)l, 16, 0, 0);
}

// ============ kernel 1: degree -> dinv = (rowsum + 1)^-1/2 ============
__global__ __launch_bounds__(256) void k_deg(const float* __restrict__ adj,
                                             float* __restrict__ dinv) {
  const int row  = blockIdx.x * 4 + (threadIdx.x >> 6);
  const int lane = threadIdx.x & 63;
  const float* p = adj + (size_t)row * N_;
  float s = 0.f;
#pragma unroll
  for (int it = 0; it < 8; ++it) {
    float4 v = *reinterpret_cast<const float4*>(p + it * 256 + lane * 4);
    s += (v.x + v.y) + (v.z + v.w);
  }
#pragma unroll
  for (int off = 32; off > 0; off >>= 1) s += __shfl_down(s, off);
  if (lane == 0) dinv[row] = 1.0f / sqrtf(s + 1.0f);
}

// ============ kernel 2: xt[b][t][f][k_swz] = bf16(d_m * x) ============
// tile-contiguous [128][64] bf16, elem (f,k) at f*64 + (k ^ ((f&7)<<3))
__global__ __launch_bounds__(256) void k_prep(const float* __restrict__ x,
                                              const float* __restrict__ dinv,
                                              unsigned short* __restrict__ xt) {
  __shared__ short s[F_ * 64];
  const int b  = blockIdx.x >> 5;
  const int t  = blockIdx.x & 31;
  const int rp = threadIdx.x >> 3;
  const int f0 = (threadIdx.x & 7) * 16;
  const int r0 = rp * 2;
  const float* x0 = x + ((size_t)(b * N_) + t * 64 + r0) * F_ + f0;
  const float d0 = dinv[b * N_ + t * 64 + r0];
  const float d1 = dinv[b * N_ + t * 64 + r0 + 1];
#pragma unroll
  for (int u = 0; u < 16; u += 4) {
    float4 v0 = *reinterpret_cast<const float4*>(x0 + u);
    float4 v1 = *reinterpret_cast<const float4*>(x0 + F_ + u);
    float a0[4] = {v0.x, v0.y, v0.z, v0.w};
    float a1[4] = {v1.x, v1.y, v1.z, v1.w};
#pragma unroll
    for (int k = 0; k < 4; ++k) {
      const int f = f0 + u + k;
      unsigned lo = (unsigned short)bfc(a0[k] * d0);
      unsigned hi = (unsigned short)bfc(a1[k] * d1);
      *reinterpret_cast<unsigned*>(&s[f * 64 + (r0 ^ ((f & 7) << 3))]) = lo | (hi << 16);
    }
  }
  __syncthreads();
  const s16x8* sp = reinterpret_cast<const s16x8*>(s);
  s16x8* op = reinterpret_cast<s16x8*>(xt + (size_t)blockIdx.x * 8192);
#pragma unroll
  for (int k = 0; k < 4; ++k) op[threadIdx.x * 4 + k] = sp[threadIdx.x * 4 + k];
}

// ============ kernel 3: fused aggregate + linear, depth-2 pipeline ============
__global__ __launch_bounds__(512, 4) void k_gcn4(const float* __restrict__ adj,
                                                 const unsigned short* __restrict__ xt,
                                                 const float* __restrict__ x,
                                                 const float* __restrict__ W,
                                                 const float* __restrict__ bias,
                                                 const float* __restrict__ dinv,
                                                 float* __restrict__ out) {
  __shared__ short s_adj[2 * 2048];   // 2 x [32][64] swizzled bf16  (8 KB)
  __shared__ short s_xt[3 * 8192];    // 3 x [128][64] swizzled bf16 (48 KB)
  short* const s_o1 = s_xt;           // epilogue alias [32][136]

  const int tid  = threadIdx.x;
  const int lane = tid & 63;
  const int wv   = tid >> 6;
  const int wrow = wv & 1;
  const int wcol = wv >> 1;

  const int batch = blockIdx.x & 7;   // batch pinned per XCD
  const int rb    = blockIdx.x >> 3;
  const int n0    = rb * BM;

  // ---- W fragments into registers (32 VGPR) ----
  s16x8 wfr[2][4];
#pragma unroll
  for (int ot = 0; ot < 2; ++ot) {
#pragma unroll
    for (int kk = 0; kk < 4; ++kk) {
      const int o  = wcol * 32 + ot * 16 + (lane & 15);
      const int f0 = kk * 32 + (lane >> 4) * 8;
      float4 v0 = *reinterpret_cast<const float4*>(W + o * F_ + f0);
      float4 v1 = *reinterpret_cast<const float4*>(W + o * F_ + f0 + 4);
      s16x8 h;
      h[0] = bfc(v0.x); h[1] = bfc(v0.y); h[2] = bfc(v0.z); h[3] = bfc(v0.w);
      h[4] = bfc(v1.x); h[5] = bfc(v1.y); h[6] = bfc(v1.z); h[7] = bfc(v1.w);
      wfr[ot][kk] = h;
    }
  }
  asm volatile("s_waitcnt vmcnt(0)" ::: "memory");
  __builtin_amdgcn_sched_barrier(0);

  // adj staging: thread owns row ai (0..31), 4 cols at aj
  const int ai = tid >> 4;
  const int aj = (tid & 15) * 4;
  const float* adj_row = adj + (size_t)(batch * N_ + n0 + ai) * N_ + aj;
  const int a_lds = ai * 64 + (aj ^ ((ai & 7) << 3));

  const unsigned short* xtb = xt + (size_t)batch * NT * 8192;

  auto issueX = [&](int t, int buf) {
    const unsigned short* src = xtb + (size_t)t * 8192;
    short* dst = s_xt + buf * 8192;
    gload16(src + tid * 8, dst + tid * 8);
    gload16(src + 4096 + tid * 8, dst + 4096 + tid * 8);
  };

  f32x4 acc[2] = {};
  float4 aA, aB;

  // prologue, issue order: [X0 x2, A0, X1 x2, A1]  (depth 2)
  issueX(0, 0);
  aA = *reinterpret_cast<const float4*>(adj_row);
  issueX(1, 1);
  aB = *reinterpret_cast<const float4*>(adj_row + BK);

  // step t: buffers — s_adj[t&1], s_xt[t%3]
  auto step = [&](int t, float4& aCur, int p, int b) {
    // stage adj tile t (compiler auto-waits aCur -> vmcnt<=3, i.e. X_t done too)
    {
      short4 h;
      h.x = bfc(aCur.x); h.y = bfc(aCur.y); h.z = bfc(aCur.z); h.w = bfc(aCur.w);
      *reinterpret_cast<short4*>(&s_adj[p * 2048 + a_lds]) = h;
    }
    if (t < NT - 1) asm volatile("s_waitcnt vmcnt(3) lgkmcnt(0)" ::: "memory");
    else            asm volatile("s_waitcnt vmcnt(0) lgkmcnt(0)" ::: "memory");
    __builtin_amdgcn_s_barrier();
    __builtin_amdgcn_sched_barrier(0);
    // window t: issue tile t+2 (X into third buffer, adj into parity reg)
    if (t + 2 < NT) {
      int b2 = b + 2; if (b2 >= 3) b2 -= 3;
      issueX(t + 2, b2);
      aCur = *reinterpret_cast<const float4*>(adj_row + (t + 2) * BK);
    }
    // compute tile t
    {
      const short* sa = &s_adj[p * 2048];
      const short* sx = &s_xt[b * 8192];
      const int row  = wrow * 16 + (lane & 15);
      const int swzr = (row & 7) << 3;
      const int krun = (lane >> 4) * 8;
      s16x8 a0 = *reinterpret_cast<const s16x8*>(sa + row * 64 + (krun ^ swzr));
      s16x8 a1 = *reinterpret_cast<const s16x8*>(sa + row * 64 + ((32 + krun) ^ swzr));
#pragma unroll
      for (int ct = 0; ct < 2; ++ct) {
        const int f    = wcol * 32 + ct * 16 + (lane & 15);
        const int swzf = (f & 7) << 3;
        s16x8 b0 = *reinterpret_cast<const s16x8*>(sx + f * 64 + (krun ^ swzf));
        s16x8 b1 = *reinterpret_cast<const s16x8*>(sx + f * 64 + ((32 + krun) ^ swzf));
        acc[ct] = __builtin_amdgcn_mfma_f32_16x16x32_bf16(a0, b0, acc[ct], 0, 0, 0);
        acc[ct] = __builtin_amdgcn_mfma_f32_16x16x32_bf16(a1, b1, acc[ct], 0, 0, 0);
      }
    }
  };

  int bc = 0;  // X buffer of tile tt (= tt % 3)
#pragma unroll 1
  for (int tt = 0; tt < NT; tt += 2) {
    step(tt, aA, 0, bc);
    int bc1 = bc + 1; if (bc1 >= 3) bc1 -= 3;
    step(tt + 1, aB, 1, bc1);
    bc = bc1 + 1; if (bc >= 3) bc -= 3;
  }

  // ---- epilogue: out1 = d_n*acc + d_n^2*x[n,f] -> bf16 LDS -> @ W^T + bias ----
  __syncthreads();
  {
    const int lr4 = (lane >> 4) * 4;
    const int lc  = lane & 15;
#pragma unroll
    for (int r = 0; r < 4; ++r) {
      const int nl = wrow * 16 + lr4 + r;
      const float dn = dinv[batch * N_ + n0 + nl];
      const float* xrow = x + (size_t)(batch * N_ + n0 + nl) * F_;
#pragma unroll
      for (int ct = 0; ct < 2; ++ct) {
        const int f = wcol * 32 + ct * 16 + lc;
        s_o1[nl * 136 + f] = bfc(dn * acc[ct][r] + dn * dn * xrow[f]);
      }
    }
  }
  __syncthreads();

  f32x4 acc2[2] = {};
  {
    const int lc   = lane & 15;
    const int krun = (lane >> 4) * 8;
#pragma unroll
    for (int kk = 0; kk < 4; ++kk) {
      s16x8 af = *reinterpret_cast<const s16x8*>(&s_o1[(wrow * 16 + lc) * 136 + kk * 32 + krun]);
#pragma unroll
      for (int ot = 0; ot < 2; ++ot)
        acc2[ot] = __builtin_amdgcn_mfma_f32_16x16x32_bf16(af, wfr[ot][kk], acc2[ot], 0, 0, 0);
    }
  }
  {
    const int lr4 = (lane >> 4) * 4;
    const int lc  = lane & 15;
#pragma unroll
    for (int ot = 0; ot < 2; ++ot) {
      const int o  = wcol * 32 + ot * 16 + lc;
      const float bb = bias[o];
#pragma unroll
      for (int r = 0; r < 4; ++r) {
        const int nl = wrow * 16 + lr4 + r;
        out[(size_t)(batch * N_ + n0 + nl) * F_ + o] = acc2[ot][r] + bb;
      }
    }
  }
}

// ============ fallback (needs only 64 KB ws) ============
__global__ __launch_bounds__(512) void k_gcn_fb(const float* __restrict__ adj,
                                                const float* __restrict__ x,
                                                const float* __restrict__ W,
                                                const float* __restrict__ bias,
                                                const float* __restrict__ dinv,
                                                float* __restrict__ out) {
  __shared__ short s_mem[64 * 72 + F_ * 72];
  __shared__ short s_w[F_ * 136];
  short* const s_adj = s_mem;
  short* const s_xb  = s_mem + 64 * 72;
  short* const s_o1  = s_mem;

  const int tid  = threadIdx.x;
  const int lane = tid & 63;
  const int wv   = tid >> 6;
  const int wrow = wv & 3;
  const int whal = wv >> 2;

  const int batch = blockIdx.x & 7;
  const int n0    = (blockIdx.x >> 3) * 64;

  {
    const int o  = tid >> 2;
    const int f0 = (tid & 3) * 32;
    const float* wp = W + o * F_ + f0;
#pragma unroll
    for (int u = 0; u < 8; ++u) {
      float4 v = *reinterpret_cast<const float4*>(wp + u * 4);
      short4 h;
      h.x = bfc(v.x); h.y = bfc(v.y); h.z = bfc(v.z); h.w = bfc(v.w);
      *reinterpret_cast<short4*>(&s_w[o * 136 + f0 + u * 4]) = h;
    }
  }

  const int ai  = tid >> 3;
  const int aj  = (tid & 7) * 8;
  const int xk2 = tid >> 4;
  const int xf0 = (tid & 15) * 8;

  const float* adj_row = adj + (size_t)(batch * N_ + n0 + ai) * N_;
  const float* x_b     = x + (size_t)batch * N_ * F_;
  const float* dv_b    = dinv + batch * N_;

  float4 ra0, ra1, rx0, rx1, rx2, rx3;
  float rd0, rd1;

  auto issue = [&](int k0) {
    ra0 = *reinterpret_cast<const float4*>(adj_row + k0 + aj);
    ra1 = *reinterpret_cast<const float4*>(adj_row + k0 + aj + 4);
    const float* xr = x_b + (size_t)(k0 + 2 * xk2) * F_ + xf0;
    rx0 = *reinterpret_cast<const float4*>(xr);
    rx1 = *reinterpret_cast<const float4*>(xr + 4);
    rx2 = *reinterpret_cast<const float4*>(xr + F_);
    rx3 = *reinterpret_cast<const float4*>(xr + F_ + 4);
    rd0 = dv_b[k0 + 2 * xk2];
    rd1 = dv_b[k0 + 2 * xk2 + 1];
  };

  f32x4 acc[4] = {};
  issue(0);
#pragma unroll 1
  for (int t = 0; t < N_ / 64; ++t) {
    __syncthreads();
    {
      s16x8 h;
      h[0] = bfc(ra0.x); h[1] = bfc(ra0.y); h[2] = bfc(ra0.z); h[3] = bfc(ra0.w);
      h[4] = bfc(ra1.x); h[5] = bfc(ra1.y); h[6] = bfc(ra1.z); h[7] = bfc(ra1.w);
      *reinterpret_cast<s16x8*>(&s_adj[ai * 72 + aj]) = h;
    }
    {
      float a0[8] = {rx0.x, rx0.y, rx0.z, rx0.w, rx1.x, rx1.y, rx1.z, rx1.w};
      float a1[8] = {rx2.x, rx2.y, rx2.z, rx2.w, rx3.x, rx3.y, rx3.z, rx3.w};
      const int kbase = (2 * xk2) ^ ((tid & 7) << 3);
#pragma unroll
      for (int u = 0; u < 8; ++u) {
        unsigned lo = (unsigned short)bfc(a0[u] * rd0);
        unsigned hi = (unsigned short)bfc(a1[u] * rd1);
        *reinterpret_cast<unsigned*>(&s_xb[(xf0 + u) * 72 + kbase]) = lo | (hi << 16);
      }
    }
    if (t + 1 < N_ / 64) issue((t + 1) * 64);
    __syncthreads();
    {
      const int arow = (wrow * 16 + (lane & 15)) * 72 + ((lane >> 4) * 8);
      s16x8 a0 = *reinterpret_cast<const s16x8*>(&s_adj[arow]);
      s16x8 a1 = *reinterpret_cast<const s16x8*>(&s_adj[arow + 32]);
      const int krun = (lane >> 4) * 8;
#pragma unroll
      for (int ct = 0; ct < 4; ++ct) {
        const int f   = whal * 64 + ct * 16 + (lane & 15);
        const int xsw = ((f >> 3) & 7) << 3;
        s16x8 b0 = *reinterpret_cast<const s16x8*>(&s_xb[f * 72 + (krun ^ xsw)]);
        s16x8 b1 = *reinterpret_cast<const s16x8*>(&s_xb[f * 72 + ((krun + 32) ^ xsw)]);
        acc[ct] = __builtin_amdgcn_mfma_f32_16x16x32_bf16(a0, b0, acc[ct], 0, 0, 0);
        acc[ct] = __builtin_amdgcn_mfma_f32_16x16x32_bf16(a1, b1, acc[ct], 0, 0, 0);
      }
    }
  }

  __syncthreads();
  {
    const int lr4 = (lane >> 4) * 4;
    const int lc  = lane & 15;
#pragma unroll
    for (int r = 0; r < 4; ++r) {
      const int nl = wrow * 16 + lr4 + r;
      const float dn = dv_b[n0 + nl];
      const float* xrow = x_b + (size_t)(n0 + nl) * F_;
#pragma unroll
      for (int ct = 0; ct < 4; ++ct) {
        const int f = whal * 64 + ct * 16 + lc;
        s_o1[nl * 136 + f] = bfc(dn * acc[ct][r] + dn * dn * xrow[f]);
      }
    }
  }
  __syncthreads();

  f32x4 acc2[4] = {};
  {
    const int lc   = lane & 15;
    const int krun = (lane >> 4) * 8;
#pragma unroll
    for (int kk = 0; kk < 4; ++kk) {
      s16x8 af = *reinterpret_cast<const s16x8*>(&s_o1[(wrow * 16 + lc) * 136 + kk * 32 + krun]);
#pragma unroll
      for (int ot = 0; ot < 4; ++ot) {
        const int o = whal * 64 + ot * 16 + lc;
        s16x8 bf8 = *reinterpret_cast<const s16x8*>(&s_w[o * 136 + kk * 32 + krun]);
        acc2[ot] = __builtin_amdgcn_mfma_f32_16x16x32_bf16(af, bf8, acc2[ot], 0, 0, 0);
      }
    }
  }
  {
    const int lr4 = (lane >> 4) * 4;
    const int lc  = lane & 15;
#pragma unroll
    for (int ot = 0; ot < 4; ++ot) {
      const int o  = whal * 64 + ot * 16 + lc;
      const float bb = bias[o];
#pragma unroll
      for (int r = 0; r < 4; ++r) {
        const int nl = wrow * 16 + lr4 + r;
        out[(size_t)(batch * N_ + n0 + nl) * F_ + o] = acc2[ot][r] + bb;
      }
    }
  }
}

extern "C" void kernel_launch(void* const* d_in, const int* in_sizes, int n_in,
                              void* d_out, int out_size, void* d_ws, size_t ws_size,
                              hipStream_t stream) {
  const float* x   = (const float*)d_in[0];
  const float* adj = (const float*)d_in[1];
  const float* W   = (const float*)d_in[2];
  const float* b   = (const float*)d_in[3];
  float* outp = (float*)d_out;
  float* dinv = (float*)d_ws;
  unsigned short* xt = (unsigned short*)((char*)d_ws + WS_XT);

  k_deg<<<(B_ * N_) / 4, 256, 0, stream>>>(adj, dinv);
  if (ws_size >= WS_XT + (size_t)B_ * NT * 8192 * 2) {
    k_prep<<<B_ * NT, 256, 0, stream>>>(x, dinv, xt);
    k_gcn4<<<B_ * NRB, 512, 0, stream>>>(adj, xt, x, W, b, dinv, outp);
  } else {
    k_gcn_fb<<<B_ * (N_ / 64), 512, 0, stream>>>(adj, x, W, b, dinv, outp);
  }
}

// Round 5
// 57.879 us; speedup vs baseline: 1.3594x; 1.0920x over previous
//
#include <hip/hip_runtime.h>
#include <hip/hip_bf16.h>

typedef __attribute__((ext_vector_type(8))) short s16x8;
typedef __attribute__((ext_vector_type(4))) float f32x4;

#define B_  8
#define N_  2048
#define F_  128
#define BM  32
#define BK  64
#define NT  (N_/BK)     // 32 k-tiles
#define NRB (N_/BM)     // 64 row-blocks per batch
#define WS_XT (65536)

__device__ __forceinline__ short bfc(float f) {
  __hip_bfloat16 h = __float2bfloat16(f);   // RNE
  return __builtin_bit_cast(short, h);
}

__device__ __forceinline__ void gload16(const void* g, void* l) {
  __builtin_amdgcn_global_load_lds(
      (const __attribute__((address_space(1))) unsigned*)g,
      (__attribute__((address_space(3))) unsigned*)l, 16, 0, 0);
}

// ============ kernel 1: FUSED degree + xt build ============
// block = (b, t): owns rows [t*64, t*64+64) of batch b.
// rowsum -> d (self-contained) -> xt tile [128 f][64 k] bf16 swizzled.
__global__ __launch_bounds__(1024) void k_degprep(const float* __restrict__ adj,
                                                  const float* __restrict__ x,
                                                  float* __restrict__ dinv,
                                                  unsigned short* __restrict__ xt) {
  __shared__ float s_d[64];
  __shared__ short s_t[F_ * 64];   // 16 KB
  const int b    = blockIdx.x >> 5;
  const int t    = blockIdx.x & 31;
  const int tid  = threadIdx.x;
  const int wv   = tid >> 6;       // 16 waves
  const int lane = tid & 63;
  const int r0g  = t * 64;

  // phase 1: rowsums (wave wv owns rows wv*4 .. wv*4+3)
#pragma unroll
  for (int i = 0; i < 4; ++i) {
    const int r = wv * 4 + i;
    const float* p = adj + ((size_t)b * N_ + r0g + r) * N_ + lane * 4;
    float s = 0.f;
#pragma unroll
    for (int it = 0; it < 8; ++it) {
      float4 v = *reinterpret_cast<const float4*>(p + it * 256);
      s += (v.x + v.y) + (v.z + v.w);
    }
    s += __shfl_xor(s, 32); s += __shfl_xor(s, 16); s += __shfl_xor(s, 8);
    s += __shfl_xor(s, 4);  s += __shfl_xor(s, 2);  s += __shfl_xor(s, 1);
    if (lane == 0) {
      const float d = 1.0f / sqrtf(s + 1.0f);
      s_d[r] = d;
      dinv[b * N_ + r0g + r] = d;
    }
  }
  __syncthreads();

  // phase 2: xt tile: elem (f,k) at f*64 + (k ^ ((f&7)<<3)), k-pairs packed as u32
  const int kp = tid >> 5;            // 0..31
  const int f0 = (tid & 31) * 4;      // 0..124
  const float d0 = s_d[2 * kp];
  const float d1 = s_d[2 * kp + 1];
  const float* x0 = x + ((size_t)(b * N_) + r0g + 2 * kp) * F_ + f0;
  float4 v0 = *reinterpret_cast<const float4*>(x0);
  float4 v1 = *reinterpret_cast<const float4*>(x0 + F_);
  float a0[4] = {v0.x, v0.y, v0.z, v0.w};
  float a1[4] = {v1.x, v1.y, v1.z, v1.w};
#pragma unroll
  for (int j = 0; j < 4; ++j) {
    const int f = f0 + j;
    unsigned lo = (unsigned short)bfc(a0[j] * d0);
    unsigned hi = (unsigned short)bfc(a1[j] * d1);
    *reinterpret_cast<unsigned*>(&s_t[f * 64 + ((2 * kp) ^ ((f & 7) << 3))]) = lo | (hi << 16);
  }
  __syncthreads();

  // dump tile: 1024 threads x 16 B
  s16x8* op = reinterpret_cast<s16x8*>(xt + (size_t)blockIdx.x * 8192);
  op[tid] = reinterpret_cast<const s16x8*>(s_t)[tid];
}

// ============ kernel 2: fused aggregate + linear (round-2 proven structure) ============
__global__ __launch_bounds__(512, 4) void k_gcn2(const float* __restrict__ adj,
                                                 const float* __restrict__ x,
                                                 const float* __restrict__ W,
                                                 const float* __restrict__ bias,
                                                 const float* __restrict__ dinv,
                                                 const unsigned short* __restrict__ xt,
                                                 float* __restrict__ out) {
  __shared__ short s_main[2 * BM * 64 + 2 * F_ * 64];  // 40960 B
  __shared__ short s_w[F_ * 136];                      // 34816 B
  short* const sadj0 = s_main;                 // [32][64] swizzled
  short* const sadj1 = s_main + 2048;
  short* const sxt0  = s_main + 4096;          // [128][64] swizzled
  short* const sxt1  = s_main + 12288;
  short* const s_o1  = s_main;                 // [32][136] epilogue alias

  const int tid  = threadIdx.x;
  const int lane = tid & 63;
  const int wv   = tid >> 6;
  const int wrow = wv & 1;    // 2 x 16 rows
  const int wcol = wv >> 1;   // 4 x 32 cols of F

  const int batch = blockIdx.x & 7;            // batch pinned per XCD
  const int n0    = (blockIdx.x >> 3) * BM;

  // ---- stage W (bf16) once: s_w[o][f], pad to 136 ----
  {
    const int o   = tid >> 2;
    const int f0c = (tid & 3) * 32;
    const float* wp = W + o * F_ + f0c;
#pragma unroll
    for (int u = 0; u < 8; ++u) {
      float4 v = *reinterpret_cast<const float4*>(wp + u * 4);
      short4 h;
      h.x = bfc(v.x); h.y = bfc(v.y); h.z = bfc(v.z); h.w = bfc(v.w);
      *reinterpret_cast<short4*>(&s_w[o * 136 + f0c + u * 4]) = h;
    }
  }
  // drain W loads so they can't pollute the counted vmcnt discipline below
  asm volatile("s_waitcnt vmcnt(0)" ::: "memory");
  __builtin_amdgcn_sched_barrier(0);

  // adj staging: thread owns row ai, 4 cols at aj
  const int ai = tid >> 4;
  const int aj = (tid & 15) * 4;
  const float* adj_row = adj + (size_t)(batch * N_ + n0 + ai) * N_ + aj;
  const int a_lds = ai * 64 + (aj ^ ((ai & 7) << 3));

  const unsigned short* xt_b = xt + (size_t)batch * NT * 8192;

  f32x4 acc[2] = {};
  float4 aA, aB;

  // prologue: issue order [A0, X0 x2, A1]
  aA = *reinterpret_cast<const float4*>(adj_row);
  gload16(xt_b + tid * 8, sxt0 + tid * 8);
  gload16(xt_b + 4096 + tid * 8, sxt0 + 4096 + tid * 8);
  aB = *reinterpret_cast<const float4*>(adj_row + BK);

  auto step = [&](int t, float4& aCur, short* sadj_c, short* sxt_c, short* sxt_n) {
    // stage adj tile t (compiler auto-waits aCur, leaving newer X/A in flight)
    {
      short4 h;
      h.x = bfc(aCur.x); h.y = bfc(aCur.y); h.z = bfc(aCur.z); h.w = bfc(aCur.w);
      *reinterpret_cast<short4*>(&sadj_c[a_lds]) = h;
    }
    // X_t arrived (leave A_{t+1} in flight); own LDS writes done
    if (t < NT - 1) asm volatile("s_waitcnt vmcnt(1) lgkmcnt(0)" ::: "memory");
    else            asm volatile("s_waitcnt vmcnt(0) lgkmcnt(0)" ::: "memory");
    __builtin_amdgcn_s_barrier();
    __builtin_amdgcn_sched_barrier(0);
    // post-barrier issues (safe: barrier proves compute t-1 done with sxt_n)
    if (t + 1 < NT) {
      const unsigned short* src = xt_b + (size_t)(t + 1) * 8192;
      gload16(src + tid * 8, sxt_n + tid * 8);
      gload16(src + 4096 + tid * 8, sxt_n + 4096 + tid * 8);
      if (t + 2 < NT) aCur = *reinterpret_cast<const float4*>(adj_row + (t + 2) * BK);
    }
    // compute: 4 MFMA / wave
    {
      const int row  = wrow * 16 + (lane & 15);
      const int swzr = (row & 7) << 3;
      const int krun = (lane >> 4) * 8;
      const short* sa = sadj_c + row * 64;
      s16x8 a0 = *reinterpret_cast<const s16x8*>(sa + (krun ^ swzr));
      s16x8 a1 = *reinterpret_cast<const s16x8*>(sa + ((32 + krun) ^ swzr));
#pragma unroll
      for (int ct = 0; ct < 2; ++ct) {
        const int f    = wcol * 32 + ct * 16 + (lane & 15);
        const int swzf = (f & 7) << 3;
        const short* sb = sxt_c + f * 64;
        s16x8 b0 = *reinterpret_cast<const s16x8*>(sb + (krun ^ swzf));
        s16x8 b1 = *reinterpret_cast<const s16x8*>(sb + ((32 + krun) ^ swzf));
        acc[ct] = __builtin_amdgcn_mfma_f32_16x16x32_bf16(a0, b0, acc[ct], 0, 0, 0);
        acc[ct] = __builtin_amdgcn_mfma_f32_16x16x32_bf16(a1, b1, acc[ct], 0, 0, 0);
      }
    }
  };

#pragma unroll 1
  for (int tt = 0; tt < NT; tt += 2) {
    step(tt,     aA, sadj0, sxt0, sxt1);
    step(tt + 1, aB, sadj1, sxt1, sxt0);
  }

  // ---- epilogue: out1 = d_n*acc + d_n^2*x[n,f] -> bf16 LDS -> @ W^T + bias ----
  __syncthreads();
  {
    const int lr4 = (lane >> 4) * 4;
    const int lc  = lane & 15;
#pragma unroll
    for (int r = 0; r < 4; ++r) {
      const int nl = wrow * 16 + lr4 + r;
      const float dn = dinv[batch * N_ + n0 + nl];
      const float* xrow = x + (size_t)(batch * N_ + n0 + nl) * F_;
#pragma unroll
      for (int ct = 0; ct < 2; ++ct) {
        const int f = wcol * 32 + ct * 16 + lc;
        s_o1[nl * 136 + f] = bfc(dn * acc[ct][r] + dn * dn * xrow[f]);
      }
    }
  }
  __syncthreads();

  f32x4 acc2[2] = {};
  {
    const int lc   = lane & 15;
    const int krun = (lane >> 4) * 8;
#pragma unroll
    for (int kk = 0; kk < 4; ++kk) {
      s16x8 af = *reinterpret_cast<const s16x8*>(&s_o1[(wrow * 16 + lc) * 136 + kk * 32 + krun]);
#pragma unroll
      for (int ot = 0; ot < 2; ++ot) {
        const int o = wcol * 32 + ot * 16 + lc;
        s16x8 bw = *reinterpret_cast<const s16x8*>(&s_w[o * 136 + kk * 32 + krun]);
        acc2[ot] = __builtin_amdgcn_mfma_f32_16x16x32_bf16(af, bw, acc2[ot], 0, 0, 0);
      }
    }
  }
  {
    const int lr4 = (lane >> 4) * 4;
    const int lc  = lane & 15;
#pragma unroll
    for (int ot = 0; ot < 2; ++ot) {
      const int o  = wcol * 32 + ot * 16 + lc;
      const float bb = bias[o];
#pragma unroll
      for (int r = 0; r < 4; ++r) {
        const int nl = wrow * 16 + lr4 + r;
        out[(size_t)(batch * N_ + n0 + nl) * F_ + o] = acc2[ot][r] + bb;
      }
    }
  }
}

// ============ fallback path (needs only 64 KB ws) ============
__global__ __launch_bounds__(256) void k_deg(const float* __restrict__ adj,
                                             float* __restrict__ dinv) {
  const int row  = blockIdx.x * 4 + (threadIdx.x >> 6);
  const int lane = threadIdx.x & 63;
  const float* p = adj + (size_t)row * N_;
  float s = 0.f;
#pragma unroll
  for (int it = 0; it < 8; ++it) {
    float4 v = *reinterpret_cast<const float4*>(p + it * 256 + lane * 4);
    s += (v.x + v.y) + (v.z + v.w);
  }
#pragma unroll
  for (int off = 32; off > 0; off >>= 1) s += __shfl_down(s, off);
  if (lane == 0) dinv[row] = 1.0f / sqrtf(s + 1.0f);
}

__global__ __launch_bounds__(512) void k_gcn_fb(const float* __restrict__ adj,
                                                const float* __restrict__ x,
                                                const float* __restrict__ W,
                                                const float* __restrict__ bias,
                                                const float* __restrict__ dinv,
                                                float* __restrict__ out) {
  __shared__ short s_mem[64 * 72 + F_ * 72];
  __shared__ short s_w[F_ * 136];
  short* const s_adj = s_mem;
  short* const s_xb  = s_mem + 64 * 72;
  short* const s_o1  = s_mem;

  const int tid  = threadIdx.x;
  const int lane = tid & 63;
  const int wv   = tid >> 6;
  const int wrow = wv & 3;
  const int whal = wv >> 2;

  const int batch = blockIdx.x & 7;
  const int n0    = (blockIdx.x >> 3) * 64;

  {
    const int o  = tid >> 2;
    const int f0 = (tid & 3) * 32;
    const float* wp = W + o * F_ + f0;
#pragma unroll
    for (int u = 0; u < 8; ++u) {
      float4 v = *reinterpret_cast<const float4*>(wp + u * 4);
      short4 h;
      h.x = bfc(v.x); h.y = bfc(v.y); h.z = bfc(v.z); h.w = bfc(v.w);
      *reinterpret_cast<short4*>(&s_w[o * 136 + f0 + u * 4]) = h;
    }
  }

  const int ai  = tid >> 3;
  const int aj  = (tid & 7) * 8;
  const int xk2 = tid >> 4;
  const int xf0 = (tid & 15) * 8;

  const float* adj_row = adj + (size_t)(batch * N_ + n0 + ai) * N_;
  const float* x_b     = x + (size_t)batch * N_ * F_;
  const float* dv_b    = dinv + batch * N_;

  float4 ra0, ra1, rx0, rx1, rx2, rx3;
  float rd0, rd1;

  auto issue = [&](int k0) {
    ra0 = *reinterpret_cast<const float4*>(adj_row + k0 + aj);
    ra1 = *reinterpret_cast<const float4*>(adj_row + k0 + aj + 4);
    const float* xr = x_b + (size_t)(k0 + 2 * xk2) * F_ + xf0;
    rx0 = *reinterpret_cast<const float4*>(xr);
    rx1 = *reinterpret_cast<const float4*>(xr + 4);
    rx2 = *reinterpret_cast<const float4*>(xr + F_);
    rx3 = *reinterpret_cast<const float4*>(xr + F_ + 4);
    rd0 = dv_b[k0 + 2 * xk2];
    rd1 = dv_b[k0 + 2 * xk2 + 1];
  };

  f32x4 acc[4] = {};
  issue(0);
#pragma unroll 1
  for (int t = 0; t < N_ / 64; ++t) {
    __syncthreads();
    {
      s16x8 h;
      h[0] = bfc(ra0.x); h[1] = bfc(ra0.y); h[2] = bfc(ra0.z); h[3] = bfc(ra0.w);
      h[4] = bfc(ra1.x); h[5] = bfc(ra1.y); h[6] = bfc(ra1.z); h[7] = bfc(ra1.w);
      *reinterpret_cast<s16x8*>(&s_adj[ai * 72 + aj]) = h;
    }
    {
      float a0[8] = {rx0.x, rx0.y, rx0.z, rx0.w, rx1.x, rx1.y, rx1.z, rx1.w};
      float a1[8] = {rx2.x, rx2.y, rx2.z, rx2.w, rx3.x, rx3.y, rx3.z, rx3.w};
      const int kbase = (2 * xk2) ^ ((tid & 7) << 3);
#pragma unroll
      for (int u = 0; u < 8; ++u) {
        unsigned lo = (unsigned short)bfc(a0[u] * rd0);
        unsigned hi = (unsigned short)bfc(a1[u] * rd1);
        *reinterpret_cast<unsigned*>(&s_xb[(xf0 + u) * 72 + kbase]) = lo | (hi << 16);
      }
    }
    if (t + 1 < N_ / 64) issue((t + 1) * 64);
    __syncthreads();
    {
      const int arow = (wrow * 16 + (lane & 15)) * 72 + ((lane >> 4) * 8);
      s16x8 a0 = *reinterpret_cast<const s16x8*>(&s_adj[arow]);
      s16x8 a1 = *reinterpret_cast<const s16x8*>(&s_adj[arow + 32]);
      const int krun = (lane >> 4) * 8;
#pragma unroll
      for (int ct = 0; ct < 4; ++ct) {
        const int f   = whal * 64 + ct * 16 + (lane & 15);
        const int xsw = ((f >> 3) & 7) << 3;
        s16x8 b0 = *reinterpret_cast<const s16x8*>(&s_xb[f * 72 + (krun ^ xsw)]);
        s16x8 b1 = *reinterpret_cast<const s16x8*>(&s_xb[f * 72 + ((krun + 32) ^ xsw)]);
        acc[ct] = __builtin_amdgcn_mfma_f32_16x16x32_bf16(a0, b0, acc[ct], 0, 0, 0);
        acc[ct] = __builtin_amdgcn_mfma_f32_16x16x32_bf16(a1, b1, acc[ct], 0, 0, 0);
      }
    }
  }

  __syncthreads();
  {
    const int lr4 = (lane >> 4) * 4;
    const int lc  = lane & 15;
#pragma unroll
    for (int r = 0; r < 4; ++r) {
      const int nl = wrow * 16 + lr4 + r;
      const float dn = dv_b[n0 + nl];
      const float* xrow = x_b + (size_t)(n0 + nl) * F_;
#pragma unroll
      for (int ct = 0; ct < 4; ++ct) {
        const int f = whal * 64 + ct * 16 + lc;
        s_o1[nl * 136 + f] = bfc(dn * acc[ct][r] + dn * dn * xrow[f]);
      }
    }
  }
  __syncthreads();

  f32x4 acc2[4] = {};
  {
    const int lc   = lane & 15;
    const int krun = (lane >> 4) * 8;
#pragma unroll
    for (int kk = 0; kk < 4; ++kk) {
      s16x8 af = *reinterpret_cast<const s16x8*>(&s_o1[(wrow * 16 + lc) * 136 + kk * 32 + krun]);
#pragma unroll
      for (int ot = 0; ot < 4; ++ot) {
        const int o = whal * 64 + ot * 16 + lc;
        s16x8 bf8 = *reinterpret_cast<const s16x8*>(&s_w[o * 136 + kk * 32 + krun]);
        acc2[ot] = __builtin_amdgcn_mfma_f32_16x16x32_bf16(af, bf8, acc2[ot], 0, 0, 0);
      }
    }
  }
  {
    const int lr4 = (lane >> 4) * 4;
    const int lc  = lane & 15;
#pragma unroll
    for (int ot = 0; ot < 4; ++ot) {
      const int o  = whal * 64 + ot * 16 + lc;
      const float bb = bias[o];
#pragma unroll
      for (int r = 0; r < 4; ++r) {
        const int nl = wrow * 16 + lr4 + r;
        out[(size_t)(batch * N_ + n0 + nl) * F_ + o] = acc2[ot][r] + bb;
      }
    }
  }
}

extern "C" void kernel_launch(void* const* d_in, const int* in_sizes, int n_in,
                              void* d_out, int out_size, void* d_ws, size_t ws_size,
                              hipStream_t stream) {
  const float* x   = (const float*)d_in[0];
  const float* adj = (const float*)d_in[1];
  const float* W   = (const float*)d_in[2];
  const float* b   = (const float*)d_in[3];
  float* outp = (float*)d_out;
  float* dinv = (float*)d_ws;
  unsigned short* xt = (unsigned short*)((char*)d_ws + WS_XT);

  if (ws_size >= WS_XT + (size_t)B_ * NT * 8192 * 2) {
    k_degprep<<<B_ * NT, 1024, 0, stream>>>(adj, x, dinv, xt);
    k_gcn2<<<B_ * NRB, 512, 0, stream>>>(adj, x, W, b, dinv, xt, outp);
  } else {
    k_deg<<<(B_ * N_) / 4, 256, 0, stream>>>(adj, dinv);
    k_gcn_fb<<<B_ * (N_ / 64), 512, 0, stream>>>(adj, x, W, b, dinv, outp);
  }
}